// Round 6
// baseline (2861.242 us; speedup 1.0000x reference)
//
#include <hip/hip_runtime.h>
#include <hip/hip_bf16.h>
#include <stdint.h>

#define BATCH 4

typedef __attribute__((ext_vector_type(8))) short bf16x8;
typedef __attribute__((ext_vector_type(4))) float f32x4;

__device__ __forceinline__ short f2b(float v) {
  __hip_bfloat16 h = __float2bfloat16(v);
  return *reinterpret_cast<short*>(&h);
}

__device__ __forceinline__ void load_lds_16B(const void* g, void* l) {
  __builtin_amdgcn_global_load_lds(
      (const __attribute__((address_space(1))) void*)g,
      (__attribute__((address_space(3))) void*)l, 16, 0, 0);
}

// ---------------- small utility kernels ----------------

__global__ void zero_buf(float* p, int n) {
  int t = blockIdx.x * 256 + threadIdx.x;
  if (t < n) p[t] = 0.f;
}

// Zero halo of a padded NHWC bf16 activation buffer [B][Hp][Wp][256].
__global__ void zero_halo(short* dst, int H, int W, int Wp, int HpWp) {
  int t = blockIdx.x * 256 + threadIdx.x;
  int cs = t & 31;
  int ppa = t >> 5;
  if (ppa >= BATCH * HpWp) return;
  int pp = ppa % HpWp;
  int py = pp / Wp, px = pp % Wp;
  if (py >= 1 && py <= H && px >= 1 && px <= W) return;
  bf16x8 z = {0, 0, 0, 0, 0, 0, 0, 0};
  *reinterpret_cast<bf16x8*>(dst + (((size_t)ppa) << 8) + (cs << 3)) = z;
}

// Repack conv weights [OC][256][3][3] f32 -> fragment-linear bf16.
// frag = ksg*noct + octile, ksg = tap*8 + icstep(32-chunk).
// lane holds B[k = icstep*32 + 8*(lane>>4)+j][oc = octile*16 + (lane&15)].
__global__ void repack_w(const float* __restrict__ src, const float* __restrict__ src2,
                         int oc_split, int oc_real, int noct, short* __restrict__ dst) {
  int t = blockIdx.x * 256 + threadIdx.x;
  if (t >= 72 * noct * 64) return;
  int lane = t & 63;
  int frag = t >> 6;
  int octile = frag % noct;
  int ksg = frag / noct;
  int tap = ksg >> 3;
  int icstep = ksg & 7;
  int oc = (octile << 4) + (lane & 15);
  int icb = (icstep << 5) + ((lane >> 4) << 3);
  bf16x8 v = {0, 0, 0, 0, 0, 0, 0, 0};
  if (oc < oc_real) {
    const float* s = (oc < oc_split ? src + (size_t)oc * 2304
                                    : src2 + (size_t)(oc - oc_split) * 2304) +
                     (size_t)icb * 9 + tap;
#pragma unroll
    for (int j = 0; j < 8; ++j) v[j] = f2b(s[j * 9]);
  }
  *reinterpret_cast<bf16x8*>(dst + (((size_t)frag) << 9) + (lane << 3)) = v;
}

// feat f32 NCHW [B][256][H][W] -> padded NHWC bf16 (interior only).
__global__ void feat_convert(const float* __restrict__ src, short* __restrict__ dst,
                             int W, int lw2, int Wp, int HpWp, int HW, int t64) {
  __shared__ __align__(16) short tile[64 * 264];
  int tid = threadIdx.x;
  int bidx = blockIdx.x;
  int b = bidx / t64;
  int p0 = (bidx - b * t64) << 6;
#pragma unroll
  for (int it = 0; it < 8; ++it) {
    int lin = it * 256 + tid;
    int c = lin >> 3;
    int pxb = (lin & 7) << 3;
    const float* s = src + ((size_t)(b * 256 + c)) * HW + p0 + pxb;
#pragma unroll
    for (int j = 0; j < 8; ++j) {
      float v = (p0 + pxb + j < HW) ? s[j] : 0.f;
      tile[(pxb + j) * 264 + c] = f2b(v);
    }
  }
  __syncthreads();
#pragma unroll
  for (int it = 0; it < 8; ++it) {
    int lin = it * 256 + tid;
    int px = lin >> 5;
    int cs = lin & 31;
    int p = p0 + px;
    if (p < HW) {
      int yy = p >> lw2, xx = p & (W - 1);
      bf16x8 o = *reinterpret_cast<const bf16x8*>(&tile[px * 264 + (cs << 3)]);
      *reinterpret_cast<bf16x8*>(dst + (((size_t)b * HpWp + (yy + 1) * Wp + xx + 1) << 8) +
                                 (cs << 3)) = o;
    }
  }
}

// GroupNorm apply + ReLU + cast: conv-out NHWC f32 -> padded NHWC bf16 interior.
__global__ void gn_apply(const float* __restrict__ y, const float* __restrict__ st,
                         const float* __restrict__ gamma, const float* __restrict__ beta,
                         short* __restrict__ dst, int HW, int W, int lw2, int Wp, int HpWp,
                         float invcnt) {
  int t = blockIdx.x * 256 + threadIdx.x;
  int cs = t & 31;
  int pp = t >> 5;
  if (pp >= BATCH * HW) return;
  int b = pp / HW;
  int p = pp - b * HW;
  int yy = p >> lw2, xx = p & (W - 1);
  int g = cs >> 1;
  float s = st[(((b << 4) + g) << 1)];
  float ss = st[(((b << 4) + g) << 1) + 1];
  float mu = s * invcnt;
  float rs = rsqrtf(ss * invcnt - mu * mu + 1e-5f);
  const f32x4* sv = reinterpret_cast<const f32x4*>(y + (((size_t)pp) << 8) + (cs << 3));
  f32x4 v0 = sv[0], v1 = sv[1];
  bf16x8 o;
#pragma unroll
  for (int j = 0; j < 8; ++j) {
    int c = (cs << 3) + j;
    float v = ((j < 4 ? v0[j & 3] : v1[j & 3]) - mu) * rs * gamma[c] + beta[c];
    o[j] = f2b(fmaxf(v, 0.f));
  }
  *reinterpret_cast<bf16x8*>(dst + (((size_t)b * HpWp + (yy + 1) * Wp + xx + 1) << 8) +
                             (cs << 3)) = o;
}

// ---------------- the conv kernel (implicit GEMM, MFMA bf16) ----------------
// X: padded NHWC bf16 [B][Hp][Wp][256].  Out tile: 128 pixels x 128 oc.
// 4 waves: wm = pixel half, wn = oc half; each wave 64px x 64oc = 4x4 16x16 frags.
// K loop: 9 taps x 4 k-tiles of 64 ic.  A staged to LDS (swizzled), B frags from global.
// EPI: 0 = tower (f32 NHWC out + GN stats), 1 = cls final (80 oc), 2 = reg final (4+1 oc).
template <int EPI>
__global__ __launch_bounds__(256) void conv_mfma(
    const short* __restrict__ X, const short* __restrict__ Wf,
    const float* __restrict__ bias, const float* __restrict__ bias2,
    float* __restrict__ out, float* __restrict__ out2, float* __restrict__ stats,
    int HW, int W, int lw2, int Wp, int HpWp, int tiles, int noct) {
  __shared__ __align__(16) short lds[2 * 8192];  // 2 x (128 px x 64 ic)
  const int tid = threadIdx.x;
  const int lane = tid & 63;
  const int wv = tid >> 6;
  const int wm = wv & 1, wn = wv >> 1;
  const int b = blockIdx.x / tiles;
  const int tile = blockIdx.x - b * tiles;
  const int p0 = tile << 7;
  const int ocb = blockIdx.y;

  // staging precompute: 4 slots/thread; gi = it*256+tid; px = gi>>3; sphys = gi&7
  int gc[4];
  int lo[4];
#pragma unroll
  for (int it = 0; it < 4; ++it) {
    int gi = it * 256 + tid;
    int px = gi >> 3, sp = gi & 7;
    int sl = sp ^ (px & 7);  // logical 16B slot whose data lands at physical sp
    int p = p0 + px;
    if (p >= HW) p = 0;
    int yy = p >> lw2, xx = p & (W - 1);
    gc[it] = ((b * HpWp + (yy + 1) * Wp + (xx + 1)) << 8) + (sl << 3);
    lo[it] = gi << 3;  // element offset within buffer
  }

  const int octbase = (ocb << 3) + (wn << 2);
  const int pxl = (wm << 6) + (lane & 15);
  const int x7 = pxl & 7;

  f32x4 acc[4][4];
#pragma unroll
  for (int m = 0; m < 4; ++m)
#pragma unroll
    for (int n = 0; n < 4; ++n) {
      acc[m][n][0] = 0.f; acc[m][n][1] = 0.f; acc[m][n][2] = 0.f; acc[m][n][3] = 0.f;
    }

  auto stage = [&](int buf, int ktg) {
    int tap = ktg >> 2, kt = ktg & 3;
    int ky = tap / 3, kx = tap - ky * 3;
    int koff = ((ky - 1) * Wp + (kx - 1)) * 256 + (kt << 6);
    short* lb = lds + buf * 8192;
#pragma unroll
    for (int it = 0; it < 4; ++it) load_lds_16B(X + gc[it] + koff, lb + lo[it]);
  };
  auto loadB = [&](bf16x8 (&br)[4][2], int ktg) {
    int tap = ktg >> 2, kt = ktg & 3;
#pragma unroll
    for (int kk = 0; kk < 2; ++kk) {
      int ksg = (tap << 3) + (kt << 1) + kk;
      const short* base = Wf + (((size_t)(ksg * noct + octbase)) << 9) + (lane << 3);
#pragma unroll
      for (int n = 0; n < 4; ++n)
        br[n][kk] = *reinterpret_cast<const bf16x8*>(base + (n << 9));
    }
  };
  auto compute = [&](int buf, bf16x8 (&br)[4][2]) {
    const short* lb = lds + buf * 8192;
#pragma unroll
    for (int kk = 0; kk < 2; ++kk) {
      int slot = ((kk << 2) + (lane >> 4)) ^ x7;
      bf16x8 af[4];
#pragma unroll
      for (int m = 0; m < 4; ++m)
        af[m] = *reinterpret_cast<const bf16x8*>(lb + ((pxl + (m << 4)) << 6) + (slot << 3));
#pragma unroll
      for (int m = 0; m < 4; ++m)
#pragma unroll
        for (int n = 0; n < 4; ++n)
          acc[m][n] = __builtin_amdgcn_mfma_f32_16x16x32_bf16(af[m], br[n][kk], acc[m][n],
                                                              0, 0, 0);
    }
  };

  bf16x8 bA[4][2], bB[4][2];
  stage(0, 0);
  loadB(bA, 0);
  __syncthreads();
#pragma unroll 1
  for (int k2 = 0; k2 < 36; k2 += 2) {
    stage(1, k2 + 1);
    loadB(bB, k2 + 1);
    compute(0, bA);
    __syncthreads();
    if (k2 + 2 < 36) {
      stage(0, k2 + 2);
      loadB(bA, k2 + 2);
    }
    compute(1, bB);
    __syncthreads();
  }

  // ---- epilogue ----
  const int col = lane & 15;
  const int rbase = (wm << 6) + ((lane >> 4) << 2);
  if (EPI == 0) {
#pragma unroll
    for (int n = 0; n < 4; ++n) {
      const int oc = (ocb << 7) + (wn << 6) + (n << 4) + col;
      const float bs = bias[oc];
      float s = 0.f, ss = 0.f;
#pragma unroll
      for (int m = 0; m < 4; ++m)
#pragma unroll
        for (int r = 0; r < 4; ++r) {
          int pr = p0 + rbase + (m << 4) + r;
          if (pr < HW) {
            float v = acc[m][n][r] + bs;
            out[(((size_t)(b * HW + pr)) << 8) + oc] = v;
            s += v;
            ss += v * v;
          }
        }
#pragma unroll
      for (int off = 32; off > 0; off >>= 1) {
        s += __shfl_xor(s, off, 64);
        ss += __shfl_xor(ss, off, 64);
      }
      if (lane == 0) {
        float* sp_ = stats + (((b << 4) + (ocb << 3) + (wn << 2) + n) << 1);
        atomicAdd(sp_, s);
        atomicAdd(sp_ + 1, ss);
      }
    }
  } else if (EPI == 1) {
#pragma unroll
    for (int n = 0; n < 4; ++n) {
      const int oc = (wn << 6) + (n << 4) + col;
      if (oc < 80) {
        const float bs = bias[oc];
#pragma unroll
        for (int m = 0; m < 4; ++m)
#pragma unroll
          for (int r = 0; r < 4; ++r) {
            int pr = p0 + rbase + (m << 4) + r;
            if (pr < HW) out[(size_t)(b * HW + pr) * 80 + oc] = acc[m][n][r] + bs;
          }
      }
    }
  } else {
#pragma unroll
    for (int n = 0; n < 4; ++n) {
      const int oc = (wn << 6) + (n << 4) + col;
      if (oc < 5) {
        const float bs = (oc < 4) ? bias[oc] : bias2[0];
#pragma unroll
        for (int m = 0; m < 4; ++m)
#pragma unroll
          for (int r = 0; r < 4; ++r) {
            int pr = p0 + rbase + (m << 4) + r;
            if (pr < HW) {
              float v = acc[m][n][r] + bs;
              if (oc < 4) out[(size_t)(b * HW + pr) * 4 + oc] = fmaxf(v, 0.f);
              else out2[b * HW + pr] = v;
            }
          }
      }
    }
  }
}

// ---------------- host ----------------

extern "C" void kernel_launch(void* const* d_in, const int* in_sizes, int n_in,
                              void* d_out, int out_size, void* d_ws, size_t ws_size,
                              hipStream_t stream) {
  static const int LH[5] = {100, 50, 25, 13, 7};
  static const int LW[5] = {128, 64, 32, 16, 8};
  static const int LS[5] = {7, 6, 5, 4, 3};
  const float* feat[5];
  for (int i = 0; i < 5; ++i) feat[i] = (const float*)d_in[i];
  const float* cls_conv_w = (const float*)d_in[5];
  const float* cls_conv_b = (const float*)d_in[6];
  const float* cls_gn_g = (const float*)d_in[7];
  const float* cls_gn_b = (const float*)d_in[8];
  const float* cls_out_w = (const float*)d_in[9];
  const float* cls_out_b = (const float*)d_in[10];
  const float* reg_conv_w = (const float*)d_in[11];
  const float* reg_conv_b = (const float*)d_in[12];
  const float* reg_gn_g = (const float*)d_in[13];
  const float* reg_gn_b = (const float*)d_in[14];
  const float* reg_bbox_w = (const float*)d_in[15];
  const float* reg_bbox_b = (const float*)d_in[16];
  const float* reg_ctr_w = (const float*)d_in[17];
  const float* reg_ctr_b = (const float*)d_in[18];
  float* out = (float*)d_out;
  char* ws = (char*)d_ws;

  const size_t WP_TOWER = 589824;  // shorts per tower conv (72*16 frags * 512)
  const size_t WP_FINAL = 294912;  // shorts per final conv (72*8 frags * 512)
  short* wpack = (short*)ws;
  const size_t OFF_STATS = 8257536;
  float* stats = (float*)(ws + OFF_STATS);
  const size_t OFF_FEAT = 8273920;
  const size_t ACT_SZ = 27156480;  // 4*102*130*256 * 2B
  short* featb = (short*)(ws + OFF_FEAT);
  short* actA = (short*)(ws + OFF_FEAT + ACT_SZ);
  short* actB = (short*)(ws + OFF_FEAT + 2 * ACT_SZ);
  float* convout = (float*)(ws + OFF_FEAT + 3 * ACT_SZ);
  if (ws_size < OFF_FEAT + 3 * ACT_SZ + 52428800) return;

  zero_buf<<<16, 256, 0, stream>>>(stats, 4096);
  for (int i = 0; i < 3; ++i)
    repack_w<<<288, 256, 0, stream>>>(cls_conv_w + (size_t)i * 589824, cls_conv_w,
                                      1 << 28, 256, 16, wpack + i * WP_TOWER);
  for (int i = 0; i < 3; ++i)
    repack_w<<<288, 256, 0, stream>>>(reg_conv_w + (size_t)i * 589824, reg_conv_w,
                                      1 << 28, 256, 16, wpack + (3 + i) * WP_TOWER);
  short* wclsf = wpack + 6 * WP_TOWER;
  short* wregf = wclsf + WP_FINAL;
  repack_w<<<144, 256, 0, stream>>>(cls_out_w, cls_out_w, 1 << 28, 80, 8, wclsf);
  repack_w<<<144, 256, 0, stream>>>(reg_bbox_w, reg_ctr_w, 4, 5, 8, wregf);

  size_t cls_off = 0, bbox_off = 5460480, ctr_off = 5733504;
  for (int L = 0; L < 5; ++L) {
    int H = LH[L], W = LW[L], HW = H * W, lw2 = LS[L];
    int Wp = W + 2, HpWp = (H + 2) * Wp;
    int tiles = (HW + 127) / 128, t64 = (HW + 63) / 64;
    int zb = (BATCH * HpWp * 32 + 255) / 256;
    zero_halo<<<zb, 256, 0, stream>>>(featb, H, W, Wp, HpWp);
    zero_halo<<<zb, 256, 0, stream>>>(actA, H, W, Wp, HpWp);
    zero_halo<<<zb, 256, 0, stream>>>(actB, H, W, Wp, HpWp);
    feat_convert<<<BATCH * t64, 256, 0, stream>>>(feat[L], featb, W, lw2, Wp, HpWp, HW, t64);
    float invc = 1.f / (16.f * HW);
    int gnblocks = (BATCH * HW * 32 + 255) / 256;
    for (int head = 0; head < 2; ++head) {
      const short* x = featb;
      const float* cb = head ? reg_conv_b : cls_conv_b;
      const float* gg = head ? reg_gn_g : cls_gn_g;
      const float* gb = head ? reg_gn_b : cls_gn_b;
      for (int i = 0; i < 3; ++i) {
        int slot = L * 6 + head * 3 + i;
        conv_mfma<0><<<dim3(BATCH * tiles, 2), 256, 0, stream>>>(
            x, wpack + (head * 3 + i) * WP_TOWER, cb + i * 256, nullptr, convout, nullptr,
            stats + slot * 128, HW, W, lw2, Wp, HpWp, tiles, 16);
        short* dst = (i & 1) ? actB : actA;
        gn_apply<<<gnblocks, 256, 0, stream>>>(convout, stats + slot * 128, gg + i * 256,
                                               gb + i * 256, dst, HW, W, lw2, Wp, HpWp, invc);
        x = dst;
      }
      if (head == 0)
        conv_mfma<1><<<dim3(BATCH * tiles, 1), 256, 0, stream>>>(
            x, wclsf, cls_out_b, nullptr, out + cls_off, nullptr, nullptr, HW, W, lw2, Wp,
            HpWp, tiles, 8);
      else
        conv_mfma<2><<<dim3(BATCH * tiles, 1), 256, 0, stream>>>(
            x, wregf, reg_bbox_b, reg_ctr_b, out + bbox_off, out + ctr_off, nullptr, HW, W,
            lw2, Wp, HpWp, tiles, 8);
    }
    cls_off += (size_t)4 * HW * 80;
    bbox_off += (size_t)4 * HW * 4;
    ctr_off += (size_t)4 * HW;
  }
}

// Round 8
// 2000.575 us; speedup vs baseline: 1.4302x; 1.4302x over previous
//
#include <hip/hip_runtime.h>
#include <hip/hip_bf16.h>
#include <stdint.h>

#define BATCH 4

typedef __attribute__((ext_vector_type(8))) short bf16x8;
typedef __attribute__((ext_vector_type(4))) float f32x4;

__device__ __forceinline__ short f2b(float v) {
  __hip_bfloat16 h = __float2bfloat16(v);
  return *reinterpret_cast<short*>(&h);
}
__device__ __forceinline__ float b2f(short s) {
  __hip_bfloat16 h = *reinterpret_cast<__hip_bfloat16*>(&s);
  return __bfloat162float(h);
}
__device__ __forceinline__ void load_lds_16B(const void* g, void* l) {
  __builtin_amdgcn_global_load_lds(
      (const __attribute__((address_space(1))) void*)g,
      (__attribute__((address_space(3))) void*)l, 16, 0, 0);
}
// m204 bijective XCD swizzle: consecutive output ids stay on one XCD.
__device__ __forceinline__ int xcd_swz(int orig, int nwg) {
  int q = nwg >> 3, r = nwg & 7;
  int xcd = orig & 7, idx = orig >> 3;
  return (xcd < r ? xcd * (q + 1) : r * (q + 1) + (xcd - r) * q) + idx;
}

// ---------------- small utility kernels ----------------

__global__ void zero_buf(float* p, int n) {
  int t = blockIdx.x * 256 + threadIdx.x;
  if (t < n) p[t] = 0.f;
}

// Zero halos of 4 padded NHWC bf16 buffers [B][Hp][Wp][256] (z selects buffer).
__global__ void zero_halo4(short* q0, short* q1, short* q2, short* q3,
                           int H, int W, int Wp, int HpWp) {
  short* dst = blockIdx.z == 0 ? q0 : blockIdx.z == 1 ? q1 : blockIdx.z == 2 ? q2 : q3;
  int t = blockIdx.x * 256 + threadIdx.x;
  int cs = t & 31;
  int ppa = t >> 5;
  if (ppa >= BATCH * HpWp) return;
  int pp = ppa % HpWp;
  int py = pp / Wp, px = pp % Wp;
  if (py >= 1 && py <= H && px >= 1 && px <= W) return;
  bf16x8 z = {0, 0, 0, 0, 0, 0, 0, 0};
  *reinterpret_cast<bf16x8*>(dst + (((size_t)ppa) << 8) + (cs << 3)) = z;
}

// Repack conv weights [OC][256][3][3] f32 -> fragment-linear bf16.
__global__ void repack_w(const float* __restrict__ src, const float* __restrict__ src2,
                         int oc_split, int oc_real, int noct, short* __restrict__ dst) {
  int t = blockIdx.x * 256 + threadIdx.x;
  if (t >= 72 * noct * 64) return;
  int lane = t & 63;
  int frag = t >> 6;
  int octile = frag % noct;
  int ksg = frag / noct;
  int tap = ksg >> 3;
  int icstep = ksg & 7;
  int oc = (octile << 4) + (lane & 15);
  int icb = (icstep << 5) + ((lane >> 4) << 3);
  bf16x8 v = {0, 0, 0, 0, 0, 0, 0, 0};
  if (oc < oc_real) {
    const float* s = (oc < oc_split ? src + (size_t)oc * 2304
                                    : src2 + (size_t)(oc - oc_split) * 2304) +
                     (size_t)icb * 9 + tap;
#pragma unroll
    for (int j = 0; j < 8; ++j) v[j] = f2b(s[j * 9]);
  }
  *reinterpret_cast<bf16x8*>(dst + (((size_t)frag) << 9) + (lane << 3)) = v;
}

// feat f32 NCHW [B][256][H][W] -> padded NHWC bf16 (interior only).
__global__ void feat_convert(const float* __restrict__ src, short* __restrict__ dst,
                             int W, int lw2, int Wp, int HpWp, int HW, int t64) {
  __shared__ __align__(16) short tile[64 * 264];
  int tid = threadIdx.x;
  int bidx = blockIdx.x;
  int b = bidx / t64;
  int p0 = (bidx - b * t64) << 6;
#pragma unroll
  for (int it = 0; it < 8; ++it) {
    int lin = it * 256 + tid;
    int c = lin >> 3;
    int pxb = (lin & 7) << 3;
    const float* s = src + ((size_t)(b * 256 + c)) * HW + p0 + pxb;
#pragma unroll
    for (int j = 0; j < 8; ++j) {
      float v = (p0 + pxb + j < HW) ? s[j] : 0.f;
      tile[(pxb + j) * 264 + c] = f2b(v);
    }
  }
  __syncthreads();
#pragma unroll
  for (int it = 0; it < 8; ++it) {
    int lin = it * 256 + tid;
    int px = lin >> 5;
    int cs = lin & 31;
    int p = p0 + px;
    if (p < HW) {
      int yy = p >> lw2, xx = p & (W - 1);
      bf16x8 o = *reinterpret_cast<const bf16x8*>(&tile[px * 264 + (cs << 3)]);
      *reinterpret_cast<bf16x8*>(dst + (((size_t)b * HpWp + (yy + 1) * Wp + xx + 1) << 8) +
                                 (cs << 3)) = o;
    }
  }
}

// In-place GroupNorm + ReLU on padded NHWC bf16 interior; z = head.
__global__ void gn_apply2(short* A0, short* A1, const float* __restrict__ st,
                          const float* __restrict__ g0, const float* __restrict__ be0,
                          const float* __restrict__ g1, const float* __restrict__ be1,
                          int HW, int W, int lw2, int Wp, int HpWp, float invcnt) {
  const int head = blockIdx.z;
  short* A = head ? A1 : A0;
  const float* gamma = head ? g1 : g0;
  const float* beta = head ? be1 : be0;
  const float* stp = st + head * 128;
  int t = blockIdx.x * 256 + threadIdx.x;
  int cs = t & 31;
  int pp = t >> 5;
  if (pp >= BATCH * HW) return;
  int b = pp / HW;
  int p = pp - b * HW;
  int yy = p >> lw2, xx = p & (W - 1);
  int g = cs >> 1;
  float s = stp[(((b << 4) + g) << 1)];
  float ss = stp[(((b << 4) + g) << 1) + 1];
  float mu = s * invcnt;
  float rs = rsqrtf(ss * invcnt - mu * mu + 1e-5f);
  short* addr = A + (((size_t)b * HpWp + (yy + 1) * Wp + xx + 1) << 8) + (cs << 3);
  bf16x8 y = *reinterpret_cast<const bf16x8*>(addr);
  bf16x8 o;
#pragma unroll
  for (int j = 0; j < 8; ++j) {
    int c = (cs << 3) + j;
    float v = (b2f(y[j]) - mu) * rs * gamma[c] + beta[c];
    o[j] = f2b(fmaxf(v, 0.f));
  }
  *reinterpret_cast<bf16x8*>(addr) = o;
}

// ---------------- tower conv (implicit GEMM, MFMA bf16, both heads via z) ----
// Tap-INNER K order (9 taps per ic-chunk consecutive -> L2/L1-hot re-reads).
// Epilogue: bias + bf16 store into padded dst interior + GN stats atomics.
__global__ __launch_bounds__(256) void conv_tower(
    const short* __restrict__ X0, const short* __restrict__ X1,
    const short* __restrict__ W0, const short* __restrict__ W1,
    const float* __restrict__ bias0, const float* __restrict__ bias1,
    short* __restrict__ D0, short* __restrict__ D1, float* __restrict__ stats,
    int HW, int W, int lw2, int Wp, int HpWp, int tiles, int nwg) {
  const int noct = 16;
  __shared__ __align__(16) short lds[2 * 8192];
  const int tid = threadIdx.x;
  const int lane = tid & 63;
  const int wv = tid >> 6;
  const int wm = wv & 1, wn = wv >> 1;
  const int head = blockIdx.z;
  const short* X = head ? X1 : X0;
  const short* Wf = head ? W1 : W0;
  const float* bias = head ? bias1 : bias0;
  short* D = head ? D1 : D0;
  float* statp = stats + head * 128;
  const int wg = xcd_swz(blockIdx.x, nwg);
  const int b = wg / tiles;
  const int tile = wg - b * tiles;
  const int p0 = tile << 7;
  const int ocb = blockIdx.y;

  int gc[4], lo[4];
#pragma unroll
  for (int it = 0; it < 4; ++it) {
    int gi = it * 256 + tid;
    int px = gi >> 3, sp = gi & 7;
    int sl = sp ^ (px & 7);
    int p = p0 + px;
    if (p >= HW) p = 0;
    int yy = p >> lw2, xx = p & (W - 1);
    gc[it] = ((b * HpWp + (yy + 1) * Wp + (xx + 1)) << 8) + (sl << 3);
    lo[it] = gi << 3;
  }
  const int octbase = (ocb << 3) + (wn << 2);
  const int pxl = (wm << 6) + (lane & 15);
  const int x7 = pxl & 7;

  f32x4 acc[4][4];
#pragma unroll
  for (int m = 0; m < 4; ++m)
#pragma unroll
    for (int n = 0; n < 4; ++n) {
      acc[m][n][0] = 0.f; acc[m][n][1] = 0.f; acc[m][n][2] = 0.f; acc[m][n][3] = 0.f;
    }

  auto stage = [&](int buf, int koff) {
    short* lb = lds + buf * 8192;
#pragma unroll
    for (int it = 0; it < 4; ++it) load_lds_16B(X + gc[it] + koff, lb + lo[it]);
  };
  auto loadB = [&](bf16x8 (&br)[4][2], int ksg0) {
#pragma unroll
    for (int kk = 0; kk < 2; ++kk) {
      const short* base = Wf + (((size_t)((ksg0 + kk) * noct + octbase)) << 9) + (lane << 3);
#pragma unroll
      for (int n = 0; n < 4; ++n)
        br[n][kk] = *reinterpret_cast<const bf16x8*>(base + (n << 9));
    }
  };
  auto compute = [&](int buf, bf16x8 (&br)[4][2]) {
    const short* lb = lds + buf * 8192;
#pragma unroll
    for (int kk = 0; kk < 2; ++kk) {
      int slot = ((kk << 2) + (lane >> 4)) ^ x7;
      bf16x8 af[4];
#pragma unroll
      for (int m = 0; m < 4; ++m)
        af[m] = *reinterpret_cast<const bf16x8*>(lb + ((pxl + (m << 4)) << 6) + (slot << 3));
#pragma unroll
      for (int m = 0; m < 4; ++m)
#pragma unroll
        for (int n = 0; n < 4; ++n)
          acc[m][n] = __builtin_amdgcn_mfma_f32_16x16x32_bf16(af[m], br[n][kk], acc[m][n],
                                                              0, 0, 0);
    }
  };

  bf16x8 bA[4][2], bB[4][2];
  stage(0, -(Wp + 1) * 256);  // phase 0: tap(0,0), kt 0
  loadB(bA, 0);
  __syncthreads();
  int kx = 1, ky = 0, kt = 0;  // counters track the NEXT phase to prefetch
#pragma unroll 1
  for (int it = 0; it < 18; ++it) {
    {
      int koff = ((ky - 1) * Wp + (kx - 1)) * 256 + kt * 64;
      stage(1, koff);
      loadB(bB, ((ky * 3 + kx) << 3) + (kt << 1));
      if (++kx == 3) { kx = 0; if (++ky == 3) { ky = 0; ++kt; } }
      compute(0, bA);
    }
    __syncthreads();
    {
      if (it < 17) {
        int koff = ((ky - 1) * Wp + (kx - 1)) * 256 + kt * 64;
        stage(0, koff);
        loadB(bA, ((ky * 3 + kx) << 3) + (kt << 1));
        if (++kx == 3) { kx = 0; if (++ky == 3) { ky = 0; ++kt; } }
      }
      compute(1, bB);
    }
    __syncthreads();
  }

  // epilogue: bias, bf16 store to padded interior, GN stats
  const int col = lane & 15;
  const int rbase = (wm << 6) + ((lane >> 4) << 2);
  const size_t bbase = (size_t)b * HpWp;
#pragma unroll
  for (int n = 0; n < 4; ++n) {
    const int oc = (ocb << 7) + (wn << 6) + (n << 4) + col;
    const float bs = bias[oc];
    float s = 0.f, ss = 0.f;
#pragma unroll
    for (int m = 0; m < 4; ++m)
#pragma unroll
      for (int r = 0; r < 4; ++r) {
        int pr = p0 + rbase + (m << 4) + r;
        if (pr < HW) {
          float v = acc[m][n][r] + bs;
          int yy = pr >> lw2, xx = pr & (W - 1);
          D[((bbase + (yy + 1) * Wp + xx + 1) << 8) + oc] = f2b(v);
          s += v;
          ss += v * v;
        }
      }
#pragma unroll
    for (int off = 32; off > 0; off >>= 1) {
      s += __shfl_xor(s, off, 64);
      ss += __shfl_xor(ss, off, 64);
    }
    if (lane == 0) {
      float* sp_ = statp + ((((b << 4) + (ocb << 3) + (wn << 2) + n)) << 1);
      atomicAdd(sp_, s);
      atomicAdd(sp_ + 1, ss);
    }
  }
}

// ---------------- final convs (cls & reg in one dispatch via z) --------------
__global__ __launch_bounds__(256) void conv_final(
    const short* __restrict__ Xc, const short* __restrict__ Xr,
    const short* __restrict__ Wc, const short* __restrict__ Wr,
    const float* __restrict__ cls_b, const float* __restrict__ bbox_b,
    const float* __restrict__ ctr_b, float* __restrict__ outc,
    float* __restrict__ outbb, float* __restrict__ outct,
    int HW, int W, int lw2, int Wp, int HpWp, int tiles, int nwg) {
  const int noct = 8;
  __shared__ __align__(16) short lds[2 * 8192];
  const int tid = threadIdx.x;
  const int lane = tid & 63;
  const int wv = tid >> 6;
  const int wm = wv & 1, wn = wv >> 1;
  const int head = blockIdx.z;
  const short* X = head ? Xr : Xc;
  const short* Wf = head ? Wr : Wc;
  const int wg = xcd_swz(blockIdx.x, nwg);
  const int b = wg / tiles;
  const int tile = wg - b * tiles;
  const int p0 = tile << 7;

  int gc[4], lo[4];
#pragma unroll
  for (int it = 0; it < 4; ++it) {
    int gi = it * 256 + tid;
    int px = gi >> 3, sp = gi & 7;
    int sl = sp ^ (px & 7);
    int p = p0 + px;
    if (p >= HW) p = 0;
    int yy = p >> lw2, xx = p & (W - 1);
    gc[it] = ((b * HpWp + (yy + 1) * Wp + (xx + 1)) << 8) + (sl << 3);
    lo[it] = gi << 3;
  }
  const int octbase = wn << 2;
  const int pxl = (wm << 6) + (lane & 15);
  const int x7 = pxl & 7;

  f32x4 acc[4][4];
#pragma unroll
  for (int m = 0; m < 4; ++m)
#pragma unroll
    for (int n = 0; n < 4; ++n) {
      acc[m][n][0] = 0.f; acc[m][n][1] = 0.f; acc[m][n][2] = 0.f; acc[m][n][3] = 0.f;
    }

  auto stage = [&](int buf, int koff) {
    short* lb = lds + buf * 8192;
#pragma unroll
    for (int it = 0; it < 4; ++it) load_lds_16B(X + gc[it] + koff, lb + lo[it]);
  };
  auto loadB = [&](bf16x8 (&br)[4][2], int ksg0) {
#pragma unroll
    for (int kk = 0; kk < 2; ++kk) {
      const short* base = Wf + (((size_t)((ksg0 + kk) * noct + octbase)) << 9) + (lane << 3);
#pragma unroll
      for (int n = 0; n < 4; ++n)
        br[n][kk] = *reinterpret_cast<const bf16x8*>(base + (n << 9));
    }
  };
  auto compute = [&](int buf, bf16x8 (&br)[4][2]) {
    const short* lb = lds + buf * 8192;
#pragma unroll
    for (int kk = 0; kk < 2; ++kk) {
      int slot = ((kk << 2) + (lane >> 4)) ^ x7;
      bf16x8 af[4];
#pragma unroll
      for (int m = 0; m < 4; ++m)
        af[m] = *reinterpret_cast<const bf16x8*>(lb + ((pxl + (m << 4)) << 6) + (slot << 3));
#pragma unroll
      for (int m = 0; m < 4; ++m)
#pragma unroll
        for (int n = 0; n < 4; ++n)
          acc[m][n] = __builtin_amdgcn_mfma_f32_16x16x32_bf16(af[m], br[n][kk], acc[m][n],
                                                              0, 0, 0);
    }
  };

  bf16x8 bA[4][2], bB[4][2];
  stage(0, -(Wp + 1) * 256);
  loadB(bA, 0);
  __syncthreads();
  int kx = 1, ky = 0, kt = 0;
#pragma unroll 1
  for (int it = 0; it < 18; ++it) {
    {
      int koff = ((ky - 1) * Wp + (kx - 1)) * 256 + kt * 64;
      stage(1, koff);
      loadB(bB, ((ky * 3 + kx) << 3) + (kt << 1));
      if (++kx == 3) { kx = 0; if (++ky == 3) { ky = 0; ++kt; } }
      compute(0, bA);
    }
    __syncthreads();
    {
      if (it < 17) {
        int koff = ((ky - 1) * Wp + (kx - 1)) * 256 + kt * 64;
        stage(0, koff);
        loadB(bA, ((ky * 3 + kx) << 3) + (kt << 1));
        if (++kx == 3) { kx = 0; if (++ky == 3) { ky = 0; ++kt; } }
      }
      compute(1, bB);
    }
    __syncthreads();
  }

  const int col = lane & 15;
  const int rbase = (wm << 6) + ((lane >> 4) << 2);
  if (head == 0) {
#pragma unroll
    for (int n = 0; n < 4; ++n) {
      const int oc = (wn << 6) + (n << 4) + col;
      if (oc < 80) {
        const float bs = cls_b[oc];
#pragma unroll
        for (int m = 0; m < 4; ++m)
#pragma unroll
          for (int r = 0; r < 4; ++r) {
            int pr = p0 + rbase + (m << 4) + r;
            if (pr < HW) outc[(size_t)(b * HW + pr) * 80 + oc] = acc[m][n][r] + bs;
          }
      }
    }
  } else {
#pragma unroll
    for (int n = 0; n < 4; ++n) {
      const int oc = (wn << 6) + (n << 4) + col;
      if (oc < 5) {
        const float bs = (oc < 4) ? bbox_b[oc] : ctr_b[0];
#pragma unroll
        for (int m = 0; m < 4; ++m)
#pragma unroll
          for (int r = 0; r < 4; ++r) {
            int pr = p0 + rbase + (m << 4) + r;
            if (pr < HW) {
              float v = acc[m][n][r] + bs;
              if (oc < 4) outbb[(size_t)(b * HW + pr) * 4 + oc] = fmaxf(v, 0.f);
              else outct[b * HW + pr] = v;
            }
          }
      }
    }
  }
}

// ---------------- host ----------------

extern "C" void kernel_launch(void* const* d_in, const int* in_sizes, int n_in,
                              void* d_out, int out_size, void* d_ws, size_t ws_size,
                              hipStream_t stream) {
  static const int LH[5] = {100, 50, 25, 13, 7};
  static const int LW[5] = {128, 64, 32, 16, 8};
  static const int LS[5] = {7, 6, 5, 4, 3};
  const float* feat[5];
  for (int i = 0; i < 5; ++i) feat[i] = (const float*)d_in[i];
  const float* cls_conv_w = (const float*)d_in[5];
  const float* cls_conv_b = (const float*)d_in[6];
  const float* cls_gn_g = (const float*)d_in[7];
  const float* cls_gn_b = (const float*)d_in[8];
  const float* cls_out_w = (const float*)d_in[9];
  const float* cls_out_b = (const float*)d_in[10];
  const float* reg_conv_w = (const float*)d_in[11];
  const float* reg_conv_b = (const float*)d_in[12];
  const float* reg_gn_g = (const float*)d_in[13];
  const float* reg_gn_b = (const float*)d_in[14];
  const float* reg_bbox_w = (const float*)d_in[15];
  const float* reg_bbox_b = (const float*)d_in[16];
  const float* reg_ctr_w = (const float*)d_in[17];
  const float* reg_ctr_b = (const float*)d_in[18];
  float* out = (float*)d_out;
  char* ws = (char*)d_ws;

  const size_t WP_TOWER = 589824;   // shorts per tower conv pack
  const size_t WP_FINAL = 294912;   // shorts per final conv pack
  short* wpack = (short*)ws;
  const size_t OFF_STATS = 8257536;
  float* stats = (float*)(ws + OFF_STATS);
  const size_t OFF_FEAT = 8273920;
  const size_t ACT_SZ = 27156480;   // 4*102*130*256 * 2B
  // featb doubles as cls's B ping buffer (safe: featb last read by merged i=0,
  // first overwritten by head0's i=1 output, which launches strictly later).
  short* featb = (short*)(ws + OFF_FEAT);   // == B0
  short* actA0 = (short*)(ws + OFF_FEAT + ACT_SZ);
  short* actA1 = (short*)(ws + OFF_FEAT + 2 * ACT_SZ);
  short* actB1 = (short*)(ws + OFF_FEAT + 3 * ACT_SZ);
  if (ws_size < OFF_FEAT + 4 * ACT_SZ) return;

  zero_buf<<<16, 256, 0, stream>>>(stats, 4096);
  for (int i = 0; i < 3; ++i)
    repack_w<<<288, 256, 0, stream>>>(cls_conv_w + (size_t)i * 589824, cls_conv_w,
                                      1 << 28, 256, 16, wpack + i * WP_TOWER);
  for (int i = 0; i < 3; ++i)
    repack_w<<<288, 256, 0, stream>>>(reg_conv_w + (size_t)i * 589824, reg_conv_w,
                                      1 << 28, 256, 16, wpack + (3 + i) * WP_TOWER);
  short* wclsf = wpack + 6 * WP_TOWER;
  short* wregf = wclsf + WP_FINAL;
  repack_w<<<144, 256, 0, stream>>>(cls_out_w, cls_out_w, 1 << 28, 80, 8, wclsf);
  repack_w<<<144, 256, 0, stream>>>(reg_bbox_w, reg_ctr_w, 4, 5, 8, wregf);

  size_t cls_off = 0, bbox_off = 5460480, ctr_off = 5733504;
  for (int L = 0; L < 5; ++L) {
    int H = LH[L], W = LW[L], HW = H * W, lw2 = LS[L];
    int Wp = W + 2, HpWp = (H + 2) * Wp;
    int tiles = (HW + 127) / 128, t64 = (HW + 63) / 64;
    int nwg = BATCH * tiles;
    int zb = (BATCH * HpWp * 32 + 255) / 256;
    zero_halo4<<<dim3(zb, 1, 4), 256, 0, stream>>>(featb, actA0, actA1, actB1, H, W, Wp,
                                                   HpWp);
    feat_convert<<<BATCH * t64, 256, 0, stream>>>(feat[L], featb, W, lw2, Wp, HpWp, HW, t64);
    float invc = 1.f / (16.f * HW);
    int gnblocks = (BATCH * HW * 32 + 255) / 256;
    // per-layer buffer schedule: head0: F->A0, A0->F, F->A0 ; head1: F->A1, A1->B1, B1->A1
    const short* s0[3] = {featb, actA0, featb};
    short* d0[3] = {actA0, featb, actA0};
    const short* s1[3] = {featb, actA1, actB1};
    short* d1[3] = {actA1, actB1, actA1};
    for (int i = 0; i < 3; ++i) {
      float* stp = stats + (size_t)(L * 3 + i) * 256;
      conv_tower<<<dim3(nwg, 2, 2), 256, 0, stream>>>(
          s0[i], s1[i], wpack + i * WP_TOWER, wpack + (3 + i) * WP_TOWER,
          cls_conv_b + i * 256, reg_conv_b + i * 256, d0[i], d1[i], stp, HW, W, lw2, Wp,
          HpWp, tiles, nwg);
      gn_apply2<<<dim3(gnblocks, 1, 2), 256, 0, stream>>>(
          d0[i], d1[i], stp, cls_gn_g + i * 256, cls_gn_b + i * 256, reg_gn_g + i * 256,
          reg_gn_b + i * 256, HW, W, lw2, Wp, HpWp, invc);
    }
    conv_final<<<dim3(nwg, 1, 2), 256, 0, stream>>>(
        actA0, actA1, wclsf, wregf, cls_out_b, reg_bbox_b, reg_ctr_b, out + cls_off,
        out + bbox_off, out + ctr_off, HW, W, lw2, Wp, HpWp, tiles, nwg);
    cls_off += (size_t)4 * HW * 80;
    bbox_off += (size_t)4 * HW * 4;
    ctr_off += (size_t)4 * HW;
  }
}

// Round 11
// 1476.228 us; speedup vs baseline: 1.9382x; 1.3552x over previous
//
#include <hip/hip_runtime.h>
#include <hip/hip_bf16.h>
#include <stdint.h>

#define BATCH 4

typedef __attribute__((ext_vector_type(8))) short bf16x8;
typedef __attribute__((ext_vector_type(4))) float f32x4;

__device__ __forceinline__ short f2b(float v) {
  __hip_bfloat16 h = __float2bfloat16(v);
  return *reinterpret_cast<short*>(&h);
}
__device__ __forceinline__ float b2f(short s) {
  __hip_bfloat16 h = *reinterpret_cast<__hip_bfloat16*>(&s);
  return __bfloat162float(h);
}
__device__ __forceinline__ void load_lds_16B(const void* g, void* l) {
  __builtin_amdgcn_global_load_lds(
      (const __attribute__((address_space(1))) void*)g,
      (__attribute__((address_space(3))) void*)l, 16, 0, 0);
}
// m204 bijective XCD swizzle.
__device__ __forceinline__ int xcd_swz(int orig, int nwg) {
  int q = nwg >> 3, r = nwg & 7;
  int xcd = orig & 7, idx = orig >> 3;
  return (xcd < r ? xcd * (q + 1) : r * (q + 1) + (xcd - r) * q) + idx;
}

// Concatenated-level geometry (all levels, batch-major inside level):
//  L:      0      1      2      3      4
//  H:    100     50     25     13      7
//  W:    128     64     32     16      8
//  HW: 12800   3200    800    208     56
//  Wp:   130     66     34     18     10
// HpWp: 13260   3432    918    270     90
// pbase (padded px incl. batch): 0, 53040, 66768, 70440, 71520  (total 71880)
// tiles(128px): 100, 25, 7, 2, 1 -> nwg cum (x4 batch): 400,500,528,536,540
// t64:          200, 50, 13, 4, 1 -> cum (x4): 800,1000,1052,1068,1072
// interior cum (x4): 51200, 64000, 67200, 68032, 68256

// ---------------- small utility kernels ----------------

__global__ void zero_buf(float* p, int n) {
  int t = blockIdx.x * 256 + threadIdx.x;
  if (t < n) p[t] = 0.f;
}

// Zero halos of the 3 concatenated act buffers (z selects buffer).
__global__ void zero_halo_cat(short* F, short* A, short* B) {
  short* dst = blockIdx.z == 0 ? F : blockIdx.z == 1 ? A : B;
  int t = blockIdx.x * 256 + threadIdx.x;
  int cs = t & 31;
  int ppa = t >> 5;
  if (ppa >= 71880) return;
  int H, W, Wp, HpWp, loc;
  if (ppa < 53040)      { loc = ppa;         H = 100; W = 128; Wp = 130; HpWp = 13260; }
  else if (ppa < 66768) { loc = ppa - 53040; H = 50;  W = 64;  Wp = 66;  HpWp = 3432; }
  else if (ppa < 70440) { loc = ppa - 66768; H = 25;  W = 32;  Wp = 34;  HpWp = 918; }
  else if (ppa < 71520) { loc = ppa - 70440; H = 13;  W = 16;  Wp = 18;  HpWp = 270; }
  else                  { loc = ppa - 71520; H = 7;   W = 8;   Wp = 10;  HpWp = 90; }
  int pp = loc % HpWp;
  int py = pp / Wp, px = pp - py * Wp;
  if (py >= 1 && py <= H && px >= 1 && px <= W) return;
  bf16x8 z = {0, 0, 0, 0, 0, 0, 0, 0};
  *reinterpret_cast<bf16x8*>(dst + (((size_t)ppa) << 8) + (cs << 3)) = z;
}

// Repack conv weights [OC][256][3][3] f32 -> fragment-linear bf16.
__global__ void repack_w(const float* __restrict__ src, const float* __restrict__ src2,
                         int oc_split, int oc_real, int noct, short* __restrict__ dst) {
  int t = blockIdx.x * 256 + threadIdx.x;
  if (t >= 72 * noct * 64) return;
  int lane = t & 63;
  int frag = t >> 6;
  int octile = frag % noct;
  int ksg = frag / noct;
  int tap = ksg >> 3;
  int icstep = ksg & 7;
  int oc = (octile << 4) + (lane & 15);
  int icb = (icstep << 5) + ((lane >> 4) << 3);
  bf16x8 v = {0, 0, 0, 0, 0, 0, 0, 0};
  if (oc < oc_real) {
    const float* s = (oc < oc_split ? src + (size_t)oc * 2304
                                    : src2 + (size_t)(oc - oc_split) * 2304) +
                     (size_t)icb * 9 + tap;
#pragma unroll
    for (int j = 0; j < 8; ++j) v[j] = f2b(s[j * 9]);
  }
  *reinterpret_cast<bf16x8*>(dst + (((size_t)frag) << 9) + (lane << 3)) = v;
}

// feat f32 NCHW -> padded NHWC bf16, all levels in one dispatch.
__global__ void feat_cat(const float* __restrict__ f0, const float* __restrict__ f1,
                         const float* __restrict__ f2, const float* __restrict__ f3,
                         const float* __restrict__ f4, short* __restrict__ dst) {
  __shared__ __align__(16) short tile[64 * 264];
  int tid = threadIdx.x;
  int wg = blockIdx.x;
  const float* src;
  int HW, W, lw2, Wp, HpWp, pbase, b, p0;
  if (wg < 800)       { int i = wg;        b = i / 200; p0 = (i - b * 200) << 6; src = f0; HW = 12800; W = 128; lw2 = 7; Wp = 130; HpWp = 13260; pbase = 0; }
  else if (wg < 1000) { int i = wg - 800;  b = i / 50;  p0 = (i - b * 50) << 6;  src = f1; HW = 3200;  W = 64;  lw2 = 6; Wp = 66;  HpWp = 3432;  pbase = 53040; }
  else if (wg < 1052) { int i = wg - 1000; b = i / 13;  p0 = (i - b * 13) << 6;  src = f2; HW = 800;   W = 32;  lw2 = 5; Wp = 34;  HpWp = 918;   pbase = 66768; }
  else if (wg < 1068) { int i = wg - 1052; b = i >> 2;  p0 = (i & 3) << 6;       src = f3; HW = 208;   W = 16;  lw2 = 4; Wp = 18;  HpWp = 270;   pbase = 70440; }
  else                { int i = wg - 1068; b = i;       p0 = 0;                  src = f4; HW = 56;    W = 8;   lw2 = 3; Wp = 10;  HpWp = 90;    pbase = 71520; }
#pragma unroll
  for (int it = 0; it < 8; ++it) {
    int lin = it * 256 + tid;
    int c = lin >> 3;
    int pxb = (lin & 7) << 3;
    const float* s = src + ((size_t)(b * 256 + c)) * HW + p0 + pxb;
#pragma unroll
    for (int j = 0; j < 8; ++j) {
      float v = (p0 + pxb + j < HW) ? s[j] : 0.f;
      tile[(pxb + j) * 264 + c] = f2b(v);
    }
  }
  __syncthreads();
#pragma unroll
  for (int it = 0; it < 8; ++it) {
    int lin = it * 256 + tid;
    int px = lin >> 5;
    int cs = lin & 31;
    int p = p0 + px;
    if (p < HW) {
      int yy = p >> lw2, xx = p & (W - 1);
      *reinterpret_cast<bf16x8*>(dst +
          (((size_t)(pbase + b * HpWp + (yy + 1) * Wp + xx + 1)) << 8) + (cs << 3)) =
          *reinterpret_cast<const bf16x8*>(&tile[px * 264 + (cs << 3)]);
    }
  }
}

// In-place GroupNorm + ReLU, all levels, both heads (z).
// st = stats + i*1280; layout [head][L][128].
__global__ void gn_cat(short* D0, short* D1, const float* __restrict__ st,
                       const float* __restrict__ g0, const float* __restrict__ be0,
                       const float* __restrict__ g1, const float* __restrict__ be1) {
  const int head = blockIdx.z;
  short* A = head ? D1 : D0;
  const float* gamma = head ? g1 : g0;
  const float* beta = head ? be1 : be0;
  int t = blockIdx.x * 256 + threadIdx.x;
  int cs = t & 31;
  int pp = t >> 5;
  if (pp >= 68256) return;
  int HW, W, lw2, Wp, HpWp, pbase, b, p, Lst;
  float invc;
  if (pp < 51200)      { int l = pp;         b = l / 12800; p = l - b * 12800; HW = 12800; W = 128; lw2 = 7; Wp = 130; HpWp = 13260; pbase = 0;     Lst = 0;   invc = 1.f / (16.f * 12800.f); }
  else if (pp < 64000) { int l = pp - 51200; b = l / 3200;  p = l - b * 3200;  HW = 3200;  W = 64;  lw2 = 6; Wp = 66;  HpWp = 3432;  pbase = 53040; Lst = 128; invc = 1.f / (16.f * 3200.f); }
  else if (pp < 67200) { int l = pp - 64000; b = l / 800;   p = l - b * 800;   HW = 800;   W = 32;  lw2 = 5; Wp = 34;  HpWp = 918;   pbase = 66768; Lst = 256; invc = 1.f / (16.f * 800.f); }
  else if (pp < 68032) { int l = pp - 67200; b = l / 208;   p = l - b * 208;   HW = 208;   W = 16;  lw2 = 4; Wp = 18;  HpWp = 270;   pbase = 70440; Lst = 384; invc = 1.f / (16.f * 208.f); }
  else                 { int l = pp - 68032; b = l / 56;    p = l - b * 56;    HW = 56;    W = 8;   lw2 = 3; Wp = 10;  HpWp = 90;    pbase = 71520; Lst = 512; invc = 1.f / (16.f * 56.f); }
  int yy = p >> lw2, xx = p & (W - 1);
  int g = cs >> 1;
  const float* stp = st + head * 640 + Lst;
  float s = stp[(((b << 4) + g) << 1)];
  float ss = stp[(((b << 4) + g) << 1) + 1];
  float mu = s * invc;
  float rs = rsqrtf(ss * invc - mu * mu + 1e-5f);
  short* addr = A + (((size_t)(pbase + b * HpWp + (yy + 1) * Wp + xx + 1)) << 8) + (cs << 3);
  bf16x8 y = *reinterpret_cast<const bf16x8*>(addr);
  bf16x8 o;
#pragma unroll
  for (int j = 0; j < 8; ++j) {
    int c = (cs << 3) + j;
    float v = (b2f(y[j]) - mu) * rs * gamma[c] + beta[c];
    o[j] = f2b(fmaxf(v, 0.f));
  }
  *reinterpret_cast<bf16x8*>(addr) = o;
}

// ---------------- tower conv: level-concat, T3/T4 ring-3 pipeline ------------
// Ring-3 LDS (48KB): A staged 2 phases ahead (global_load_lds, swizzled source),
// B-frags 1 phase ahead (regs, compiler-counted waits). Phase p:
//   issue stage(p+2), loadB(p+1); s_waitcnt vmcnt(12) [A(p),B(p) done];
//   s_barrier (all waves' A(p) in LDS); sched_barrier; compute(p); s_barrier.
// Trailing barrier makes ring-3 WAR-safe: stage(p+2) (issued at phase p, after
// passing barrier#2(p-1)) overwrites slot (p-1)%3, whose readers (compute(p-1))
// all finished before barrier#2(p-1). Tail counts: phase 34 -> vmcnt(8),
// phase 35 -> vmcnt(0).
__global__ __launch_bounds__(256) void conv_tower(
    const short* __restrict__ X, const short* __restrict__ Wf,
    const float* __restrict__ bias, short* __restrict__ D,
    float* __restrict__ stats) {
  const int noct = 16;
  __shared__ __align__(16) short lds[3 * 8192];
  const int tid = threadIdx.x;
  const int lane = tid & 63;
  const int wv = tid >> 6;
  const int wm = wv & 1, wn = wv >> 1;
  const int ocb = blockIdx.y;
  int wg = xcd_swz(blockIdx.x, 540);
  int HW, W, lw2, Wp, HpWp, pbase, b, tile, Lst;
  if (wg < 400)      { int i = wg;       b = i / 100; tile = i - b * 100; HW = 12800; W = 128; lw2 = 7; Wp = 130; HpWp = 13260; pbase = 0;     Lst = 0; }
  else if (wg < 500) { int i = wg - 400; b = i / 25;  tile = i - b * 25;  HW = 3200;  W = 64;  lw2 = 6; Wp = 66;  HpWp = 3432;  pbase = 53040; Lst = 128; }
  else if (wg < 528) { int i = wg - 500; b = i / 7;   tile = i - b * 7;   HW = 800;   W = 32;  lw2 = 5; Wp = 34;  HpWp = 918;   pbase = 66768; Lst = 256; }
  else if (wg < 536) { int i = wg - 528; b = i >> 1;  tile = i & 1;       HW = 208;   W = 16;  lw2 = 4; Wp = 18;  HpWp = 270;   pbase = 70440; Lst = 384; }
  else               { int i = wg - 536; b = i;       tile = 0;           HW = 56;    W = 8;   lw2 = 3; Wp = 10;  HpWp = 90;    pbase = 71520; Lst = 512; }
  const int p0 = tile << 7;

  int gc[4], lo[4];
#pragma unroll
  for (int it = 0; it < 4; ++it) {
    int gi = it * 256 + tid;
    int px = gi >> 3, sp = gi & 7;
    int sl = sp ^ (px & 7);
    int p = p0 + px;
    if (p >= HW) p = 0;
    int yy = p >> lw2, xx = p & (W - 1);
    gc[it] = ((pbase + b * HpWp + (yy + 1) * Wp + (xx + 1)) << 8) + (sl << 3);
    lo[it] = gi << 3;
  }
  const int octbase = (ocb << 3) + (wn << 2);
  const int pxl = (wm << 6) + (lane & 15);
  const int x7 = pxl & 7;

  f32x4 acc[4][4];
#pragma unroll
  for (int m = 0; m < 4; ++m)
#pragma unroll
    for (int n = 0; n < 4; ++n) {
      acc[m][n][0] = 0.f; acc[m][n][1] = 0.f; acc[m][n][2] = 0.f; acc[m][n][3] = 0.f;
    }

  // phase p -> (kt = p/9, tap = p%9): tap-inner order for L2 locality.
  auto koff_of = [&](int p) -> int {
    int kt = p / 9; int tap = p - kt * 9; int ky = tap / 3; int kx = tap - ky * 3;
    return ((ky - 1) * Wp + (kx - 1)) * 256 + kt * 64;
  };
  auto ksg_of = [&](int p) -> int {
    int kt = p / 9; int tap = p - kt * 9; return (tap << 3) + (kt << 1);
  };
  auto stage = [&](int slot, int koff) {
    short* lb = lds + slot * 8192;
#pragma unroll
    for (int it = 0; it < 4; ++it) load_lds_16B(X + gc[it] + koff, lb + lo[it]);
  };
  auto loadB = [&](bf16x8 (&br)[4][2], int ksg0) {
#pragma unroll
    for (int kk = 0; kk < 2; ++kk) {
      const short* base = Wf + (((size_t)((ksg0 + kk) * noct + octbase)) << 9) + (lane << 3);
#pragma unroll
      for (int n = 0; n < 4; ++n)
        br[n][kk] = *reinterpret_cast<const bf16x8*>(base + (n << 9));
    }
  };
  auto compute = [&](int slot, bf16x8 (&br)[4][2]) {
    const short* lb = lds + slot * 8192;
#pragma unroll
    for (int kk = 0; kk < 2; ++kk) {
      int sl = ((kk << 2) + (lane >> 4)) ^ x7;
      bf16x8 af[4];
#pragma unroll
      for (int m = 0; m < 4; ++m)
        af[m] = *reinterpret_cast<const bf16x8*>(lb + ((pxl + (m << 4)) << 6) + (sl << 3));
#pragma unroll
      for (int m = 0; m < 4; ++m)
#pragma unroll
        for (int n = 0; n < 4; ++n)
          acc[m][n] = __builtin_amdgcn_mfma_f32_16x16x32_bf16(af[m], br[n][kk], acc[m][n],
                                                              0, 0, 0);
    }
  };

  bf16x8 bA[4][2], bB[4][2];
  stage(0, koff_of(0));
  stage(1, koff_of(1));
  loadB(bA, ksg_of(0));
  int sw = 2, sr = 0;
#pragma unroll 1
  for (int T = 0; T < 18; ++T) {
    int p = 2 * T;
    // ---- even phase p: compute bA ----
    if (p + 2 < 36) { stage(sw, koff_of(p + 2)); if (++sw == 3) sw = 0; }
    loadB(bB, ksg_of(p + 1));
    if (T < 17) asm volatile("s_waitcnt vmcnt(12)" ::: "memory");
    else        asm volatile("s_waitcnt vmcnt(8)" ::: "memory");
    __builtin_amdgcn_s_barrier();
    __builtin_amdgcn_sched_barrier(0);
    compute(sr, bA); if (++sr == 3) sr = 0;
    __builtin_amdgcn_s_barrier();
    // ---- odd phase p+1: compute bB ----
    if (p + 3 < 36) { stage(sw, koff_of(p + 3)); if (++sw == 3) sw = 0; }
    if (p + 2 < 36) loadB(bA, ksg_of(p + 2));
    if (T < 17) asm volatile("s_waitcnt vmcnt(12)" ::: "memory");
    else        asm volatile("s_waitcnt vmcnt(0)" ::: "memory");
    __builtin_amdgcn_s_barrier();
    __builtin_amdgcn_sched_barrier(0);
    compute(sr, bB); if (++sr == 3) sr = 0;
    __builtin_amdgcn_s_barrier();
  }

  // epilogue: bias, bf16 store to padded interior, GN stats
  const int col = lane & 15;
  const int rbase = (wm << 6) + ((lane >> 4) << 2);
  float* statp = stats + Lst;
#pragma unroll
  for (int n = 0; n < 4; ++n) {
    const int oc = (ocb << 7) + (wn << 6) + (n << 4) + col;
    const float bs = bias[oc];
    float s = 0.f, ss = 0.f;
#pragma unroll
    for (int m = 0; m < 4; ++m)
#pragma unroll
      for (int r = 0; r < 4; ++r) {
        int pr = p0 + rbase + (m << 4) + r;
        if (pr < HW) {
          float v = acc[m][n][r] + bs;
          int yy = pr >> lw2, xx = pr & (W - 1);
          D[(((size_t)(pbase + b * HpWp + (yy + 1) * Wp + xx + 1)) << 8) + oc] = f2b(v);
          s += v;
          ss += v * v;
        }
      }
#pragma unroll
    for (int off = 32; off > 0; off >>= 1) {
      s += __shfl_xor(s, off, 64);
      ss += __shfl_xor(ss, off, 64);
    }
    if (lane == 0) {
      float* sp_ = statp + ((((b << 4) + (ocb << 3) + (wn << 2) + n)) << 1);
      atomicAdd(sp_, s);
      atomicAdd(sp_ + 1, ss);
    }
  }
}

// ---------------- final convs: level-concat, both heads (z), same ring ------
__global__ __launch_bounds__(256) void conv_final(
    const short* __restrict__ Xc, const short* __restrict__ Xr,
    const short* __restrict__ Wc, const short* __restrict__ Wr,
    const float* __restrict__ cls_b, const float* __restrict__ bbox_b,
    const float* __restrict__ ctr_b, float* __restrict__ out) {
  const int noct = 8;
  __shared__ __align__(16) short lds[3 * 8192];
  const int tid = threadIdx.x;
  const int lane = tid & 63;
  const int wv = tid >> 6;
  const int wm = wv & 1, wn = wv >> 1;
  const int head = blockIdx.z;
  const short* X = head ? Xr : Xc;
  const short* Wf = head ? Wr : Wc;
  int wg = xcd_swz(blockIdx.x, 540);
  int HW, W, lw2, Wp, HpWp, pbase, b, tile, co, bo, to;
  if (wg < 400)      { int i = wg;       b = i / 100; tile = i - b * 100; HW = 12800; W = 128; lw2 = 7; Wp = 130; HpWp = 13260; pbase = 0;     co = 0;       bo = 0;      to = 0; }
  else if (wg < 500) { int i = wg - 400; b = i / 25;  tile = i - b * 25;  HW = 3200;  W = 64;  lw2 = 6; Wp = 66;  HpWp = 3432;  pbase = 53040; co = 4096000; bo = 204800; to = 51200; }
  else if (wg < 528) { int i = wg - 500; b = i / 7;   tile = i - b * 7;   HW = 800;   W = 32;  lw2 = 5; Wp = 34;  HpWp = 918;   pbase = 66768; co = 5120000; bo = 256000; to = 64000; }
  else if (wg < 536) { int i = wg - 528; b = i >> 1;  tile = i & 1;       HW = 208;   W = 16;  lw2 = 4; Wp = 18;  HpWp = 270;   pbase = 70440; co = 5376000; bo = 268800; to = 67200; }
  else               { int i = wg - 536; b = i;       tile = 0;           HW = 56;    W = 8;   lw2 = 3; Wp = 10;  HpWp = 90;    pbase = 71520; co = 5442560; bo = 272128; to = 68032; }
  const int p0 = tile << 7;
  float* outc = out + co;
  float* outbb = out + 5460480 + bo;
  float* outct = out + 5733504 + to;

  int gc[4], lo[4];
#pragma unroll
  for (int it = 0; it < 4; ++it) {
    int gi = it * 256 + tid;
    int px = gi >> 3, sp = gi & 7;
    int sl = sp ^ (px & 7);
    int p = p0 + px;
    if (p >= HW) p = 0;
    int yy = p >> lw2, xx = p & (W - 1);
    gc[it] = ((pbase + b * HpWp + (yy + 1) * Wp + (xx + 1)) << 8) + (sl << 3);
    lo[it] = gi << 3;
  }
  const int octbase = wn << 2;
  const int pxl = (wm << 6) + (lane & 15);
  const int x7 = pxl & 7;

  f32x4 acc[4][4];
#pragma unroll
  for (int m = 0; m < 4; ++m)
#pragma unroll
    for (int n = 0; n < 4; ++n) {
      acc[m][n][0] = 0.f; acc[m][n][1] = 0.f; acc[m][n][2] = 0.f; acc[m][n][3] = 0.f;
    }

  auto koff_of = [&](int p) -> int {
    int kt = p / 9; int tap = p - kt * 9; int ky = tap / 3; int kx = tap - ky * 3;
    return ((ky - 1) * Wp + (kx - 1)) * 256 + kt * 64;
  };
  auto ksg_of = [&](int p) -> int {
    int kt = p / 9; int tap = p - kt * 9; return (tap << 3) + (kt << 1);
  };
  auto stage = [&](int slot, int koff) {
    short* lb = lds + slot * 8192;
#pragma unroll
    for (int it = 0; it < 4; ++it) load_lds_16B(X + gc[it] + koff, lb + lo[it]);
  };
  auto loadB = [&](bf16x8 (&br)[4][2], int ksg0) {
#pragma unroll
    for (int kk = 0; kk < 2; ++kk) {
      const short* base = Wf + (((size_t)((ksg0 + kk) * noct + octbase)) << 9) + (lane << 3);
#pragma unroll
      for (int n = 0; n < 4; ++n)
        br[n][kk] = *reinterpret_cast<const bf16x8*>(base + (n << 9));
    }
  };
  auto compute = [&](int slot, bf16x8 (&br)[4][2]) {
    const short* lb = lds + slot * 8192;
#pragma unroll
    for (int kk = 0; kk < 2; ++kk) {
      int sl = ((kk << 2) + (lane >> 4)) ^ x7;
      bf16x8 af[4];
#pragma unroll
      for (int m = 0; m < 4; ++m)
        af[m] = *reinterpret_cast<const bf16x8*>(lb + ((pxl + (m << 4)) << 6) + (sl << 3));
#pragma unroll
      for (int m = 0; m < 4; ++m)
#pragma unroll
        for (int n = 0; n < 4; ++n)
          acc[m][n] = __builtin_amdgcn_mfma_f32_16x16x32_bf16(af[m], br[n][kk], acc[m][n],
                                                              0, 0, 0);
    }
  };

  bf16x8 bA[4][2], bB[4][2];
  stage(0, koff_of(0));
  stage(1, koff_of(1));
  loadB(bA, ksg_of(0));
  int sw = 2, sr = 0;
#pragma unroll 1
  for (int T = 0; T < 18; ++T) {
    int p = 2 * T;
    if (p + 2 < 36) { stage(sw, koff_of(p + 2)); if (++sw == 3) sw = 0; }
    loadB(bB, ksg_of(p + 1));
    if (T < 17) asm volatile("s_waitcnt vmcnt(12)" ::: "memory");
    else        asm volatile("s_waitcnt vmcnt(8)" ::: "memory");
    __builtin_amdgcn_s_barrier();
    __builtin_amdgcn_sched_barrier(0);
    compute(sr, bA); if (++sr == 3) sr = 0;
    __builtin_amdgcn_s_barrier();
    if (p + 3 < 36) { stage(sw, koff_of(p + 3)); if (++sw == 3) sw = 0; }
    if (p + 2 < 36) loadB(bA, ksg_of(p + 2));
    if (T < 17) asm volatile("s_waitcnt vmcnt(12)" ::: "memory");
    else        asm volatile("s_waitcnt vmcnt(0)" ::: "memory");
    __builtin_amdgcn_s_barrier();
    __builtin_amdgcn_sched_barrier(0);
    compute(sr, bB); if (++sr == 3) sr = 0;
    __builtin_amdgcn_s_barrier();
  }

  const int col = lane & 15;
  const int rbase = (wm << 6) + ((lane >> 4) << 2);
  if (head == 0) {
#pragma unroll
    for (int n = 0; n < 4; ++n) {
      const int oc = (wn << 6) + (n << 4) + col;
      if (oc < 80) {
        const float bs = cls_b[oc];
#pragma unroll
        for (int m = 0; m < 4; ++m)
#pragma unroll
          for (int r = 0; r < 4; ++r) {
            int pr = p0 + rbase + (m << 4) + r;
            if (pr < HW) outc[(size_t)(b * HW + pr) * 80 + oc] = acc[m][n][r] + bs;
          }
      }
    }
  } else {
#pragma unroll
    for (int n = 0; n < 4; ++n) {
      const int oc = (wn << 6) + (n << 4) + col;
      if (oc < 5) {
        const float bs = (oc < 4) ? bbox_b[oc] : ctr_b[0];
#pragma unroll
        for (int m = 0; m < 4; ++m)
#pragma unroll
          for (int r = 0; r < 4; ++r) {
            int pr = p0 + rbase + (m << 4) + r;
            if (pr < HW) {
              float v = acc[m][n][r] + bs;
              if (oc < 4) outbb[(size_t)(b * HW + pr) * 4 + oc] = fmaxf(v, 0.f);
              else outct[b * HW + pr] = v;
            }
          }
      }
    }
  }
}

// ---------------- host ----------------

extern "C" void kernel_launch(void* const* d_in, const int* in_sizes, int n_in,
                              void* d_out, int out_size, void* d_ws, size_t ws_size,
                              hipStream_t stream) {
  const float* feat0 = (const float*)d_in[0];
  const float* feat1 = (const float*)d_in[1];
  const float* feat2 = (const float*)d_in[2];
  const float* feat3 = (const float*)d_in[3];
  const float* feat4 = (const float*)d_in[4];
  const float* cls_conv_w = (const float*)d_in[5];
  const float* cls_conv_b = (const float*)d_in[6];
  const float* cls_gn_g = (const float*)d_in[7];
  const float* cls_gn_b = (const float*)d_in[8];
  const float* cls_out_w = (const float*)d_in[9];
  const float* cls_out_b = (const float*)d_in[10];
  const float* reg_conv_w = (const float*)d_in[11];
  const float* reg_conv_b = (const float*)d_in[12];
  const float* reg_gn_g = (const float*)d_in[13];
  const float* reg_gn_b = (const float*)d_in[14];
  const float* reg_bbox_w = (const float*)d_in[15];
  const float* reg_bbox_b = (const float*)d_in[16];
  const float* reg_ctr_w = (const float*)d_in[17];
  const float* reg_ctr_b = (const float*)d_in[18];
  float* out = (float*)d_out;
  char* ws = (char*)d_ws;

  const size_t WP_TOWER = 589824;   // shorts per tower conv pack
  const size_t WP_FINAL = 294912;   // shorts per final conv pack
  short* wpack = (short*)ws;
  const size_t OFF_STATS = 8257536;
  float* stats = (float*)(ws + OFF_STATS);  // [i][head][L][128] = 3840 floats
  const size_t OFF_FEAT = 8273920;
  const size_t ACT_SZ = 36802560;   // 71880 px * 256 ch * 2B
  short* Fb = (short*)(ws + OFF_FEAT);
  short* Ab = (short*)(ws + OFF_FEAT + ACT_SZ);
  short* Bb = (short*)(ws + OFF_FEAT + 2 * ACT_SZ);
  if (ws_size < OFF_FEAT + 3 * ACT_SZ) return;  // 118.7 MB, under proven budget

  zero_buf<<<15, 256, 0, stream>>>(stats, 3840);
  for (int i = 0; i < 3; ++i)
    repack_w<<<288, 256, 0, stream>>>(cls_conv_w + (size_t)i * 589824, cls_conv_w,
                                      1 << 28, 256, 16, wpack + i * WP_TOWER);
  for (int i = 0; i < 3; ++i)
    repack_w<<<288, 256, 0, stream>>>(reg_conv_w + (size_t)i * 589824, reg_conv_w,
                                      1 << 28, 256, 16, wpack + (3 + i) * WP_TOWER);
  short* wclsf = wpack + 6 * WP_TOWER;
  short* wregf = wclsf + WP_FINAL;
  repack_w<<<144, 256, 0, stream>>>(cls_out_w, cls_out_w, 1 << 28, 80, 8, wclsf);
  repack_w<<<144, 256, 0, stream>>>(reg_bbox_w, reg_ctr_w, 4, 5, 8, wregf);

  zero_halo_cat<<<dim3(8985, 1, 3), 256, 0, stream>>>(Fb, Ab, Bb);
  feat_cat<<<1072, 256, 0, stream>>>(feat0, feat1, feat2, feat3, feat4, Fb);

  // 3-buffer schedule (heads sequential, stream-serialized):
  //  i0: h0 F->A ; h1 F->B ; gn(A,B)
  //  i1: h0 A->F ; h1 B->A ; gn(F,A)
  //  i2: h0 F->B ; h1 A->F ; gn(B,F)
  //  final: cls from B, reg from F
  const short* XS0[3] = {Fb, Ab, Fb};
  short* DS0[3] = {Ab, Fb, Bb};
  const short* XS1[3] = {Fb, Bb, Ab};
  short* DS1[3] = {Bb, Ab, Fb};
  for (int i = 0; i < 3; ++i) {
    float* stp = stats + (size_t)i * 1280;
    conv_tower<<<dim3(540, 2), 256, 0, stream>>>(
        XS0[i], wpack + i * WP_TOWER, cls_conv_b + i * 256, DS0[i], stp);
    conv_tower<<<dim3(540, 2), 256, 0, stream>>>(
        XS1[i], wpack + (3 + i) * WP_TOWER, reg_conv_b + i * 256, DS1[i], stp + 640);
    gn_cat<<<dim3(8532, 1, 2), 256, 0, stream>>>(
        DS0[i], DS1[i], stp, cls_gn_g + i * 256, cls_gn_b + i * 256, reg_gn_g + i * 256,
        reg_gn_b + i * 256);
  }
  conv_final<<<dim3(540, 1, 2), 256, 0, stream>>>(
      Bb, Fb, wclsf, wregf, cls_out_b, reg_bbox_b, reg_ctr_b, out);
}